// Round 5
// baseline (322.296 us; speedup 1.0000x reference)
//
#include <hip/hip_runtime.h>

#define B_ 2
#define T_ 2048
#define NH 16
#define NKV 8
#define HD 128
#define C_ 2048
#define KVD (NKV*HD)       // 1024
#define QKVD (C_ + 2*KVD)  // 4096
#define NTOK (B_*T_)       // 4096

typedef __bf16 bf16_t;
typedef __bf16 bf16x2_t __attribute__((ext_vector_type(2)));
typedef __bf16 bf16x4_t __attribute__((ext_vector_type(4)));
typedef __bf16 bf16x8_t __attribute__((ext_vector_type(8)));
typedef float f32x4_t __attribute__((ext_vector_type(4)));
typedef float f32x16_t __attribute__((ext_vector_type(16)));
typedef int i32x4_t __attribute__((ext_vector_type(4)));

__device__ __forceinline__ f32x4_t mfma16(bf16x8_t a, bf16x8_t b, f32x4_t c) {
  return __builtin_amdgcn_mfma_f32_16x16x32_bf16(a, b, c, 0, 0, 0);
}
__device__ __forceinline__ f32x16_t mfma32(bf16x8_t a, bf16x8_t b, f32x16_t c) {
  return __builtin_amdgcn_mfma_f32_32x32x16_bf16(a, b, c, 0, 0, 0);
}
__device__ __forceinline__ f32x16_t zero16() {
  f32x16_t z;
  #pragma unroll
  for (int i = 0; i < 16; i++) z[i] = 0.f;
  return z;
}
__device__ __forceinline__ int pk2(float a, float b) {
  bf16x2_t t; t[0] = (bf16_t)a; t[1] = (bf16_t)b;
  return __builtin_bit_cast(int, t);
}

// async global->LDS, 16B per lane
#define GLDS16(gp, lp) __builtin_amdgcn_global_load_lds( \
    (const __attribute__((address_space(1))) void*)(gp), \
    (__attribute__((address_space(3))) void*)(lp), 16, 0, 0)

#define CFENCE() asm volatile("" ::: "memory")

// ---------------- fused fp32 -> bf16 convert for x / w_attn / w_proj ----------------
__global__ __launch_bounds__(256) void cvt3_kernel(const float* __restrict__ s0, bf16_t* __restrict__ d0,
                                                   const float* __restrict__ s1, bf16_t* __restrict__ d1,
                                                   const float* __restrict__ s2, bf16_t* __restrict__ d2) {
  int bid = blockIdx.x;
  const float* s; bf16_t* d; int off;
  if (bid < 8192)       { s = s0; d = d0; off = bid; }
  else if (bid < 16384) { s = s1; d = d1; off = bid - 8192; }
  else                  { s = s2; d = d2; off = bid - 16384; }
  int i = (off * 256 + threadIdx.x) * 4;
  const float4 v = *(const float4*)(s + i);
  bf16x4_t o;
  o[0] = (bf16_t)v.x; o[1] = (bf16_t)v.y; o[2] = (bf16_t)v.z; o[3] = (bf16_t)v.w;
  *(bf16x4_t*)(d + i) = o;
}

// ---------------- 8-phase 256x256 bf16 NT GEMM (T1+T2+T3+T4+T5): C = A B^T, bf16 out ----------------
// 512 threads = 8 waves (2M x 4N); per-wave C = 128 x 64 (acc[8][4] 16x16 frags).
// BK=64; LDS = 2dbuf x (256x64) x {A,B} x 2B = 128 KiB -> 1 block/CU, 2 waves/SIMD.
// Per K-tile: 4 phases. Phase j: {ds_read A-frag pair j (4 b128; phase 0 also B-frags 8 b128,
// held in regs all tile) | stage ONE half-tile (2 GLDS16) | s_barrier | setprio(1) 16 MFMA
// setprio(0) | s_barrier}. Staging stream (race-analyzed):
//   phase 0: A-half0(s+1)  [old A0 of that buf last read at tile s-1 phase 3 -> done]
//   phase 1: A-half1(s+1)
//   phase 2: B-half0(s+2) into buf (s&1)  [this tile's B reads completed at phase 0]
//   phase 3: B-half1(s+2); then s_waitcnt vmcnt(4): leaves B(s+2) (4 loads) in flight,
//            guarantees A(s+1)+B(s+1) landed; following barrier publishes to all waves.
// Counted vmcnt ONCE per K-tile, never 0 in steady state (T4). Raw s_barrier (no drain);
// lgkmcnt is compiler-managed (plain LDS loads -> SSA deps; no rule-#18 hazard).
// T2 swizzle: LDS[row][blk] holds global[row][blk^(row&7)] via inverse-swizzled global source
// (GLDS dest linear, rule #21); reads XOR with l16&7. T1: bijective XCD swizzle (nwg%8==0).
__global__ __launch_bounds__(512, 1) void gemm8p(const bf16_t* __restrict__ A,
                                                 const bf16_t* __restrict__ Bm,
                                                 bf16_t* __restrict__ Cb,
                                                 int M, int N, int K) {
  __shared__ __align__(16) bf16_t As[2][256 * 64];
  __shared__ __align__(16) bf16_t Bs[2][256 * 64];
  int tid = threadIdx.x;
  int wave = tid >> 6, lane = tid & 63;
  int quad = lane >> 4, l16 = lane & 15;
  int wm = wave >> 2, wn = wave & 3;
  int gx = gridDim.x, nwg = gx * gridDim.y;
  int flat = blockIdx.y * gx + blockIdx.x;
  int swz = (flat & 7) * (nwg >> 3) + (flat >> 3);
  int bm = (swz / gx) * 256, bn = (swz % gx) * 256;
  // staging: lane covers row srow (within 64-row round), source col-block inverse-swizzled
  int scol = ((tid & 7) ^ ((tid >> 3) & 7)) * 8;
  int srow = tid >> 3;                 // 0..63
  const bf16_t* pa = A + (size_t)(bm + srow) * K + scol;
  const bf16_t* pb = Bm + (size_t)(bn + srow) * K + scol;

#define STAGE_A8(buf, tile, h) { \
    GLDS16(pa + (size_t)((h)*128 + 0) * K + (size_t)(tile)*64, &As[buf][((h)*128 + 0 + wave*8)*64]); \
    GLDS16(pa + (size_t)((h)*128 + 64) * K + (size_t)(tile)*64, &As[buf][((h)*128 + 64 + wave*8)*64]); }
#define STAGE_B8(buf, tile, h) { \
    GLDS16(pb + (size_t)((h)*128 + 0) * K + (size_t)(tile)*64, &Bs[buf][((h)*128 + 0 + wave*8)*64]); \
    GLDS16(pb + (size_t)((h)*128 + 64) * K + (size_t)(tile)*64, &Bs[buf][((h)*128 + 64 + wave*8)*64]); }

  f32x4_t acc[8][4];
  #pragma unroll
  for (int i = 0; i < 8; i++)
    #pragma unroll
    for (int j = 0; j < 4; j++) acc[i][j] = (f32x4_t){0.f, 0.f, 0.f, 0.f};

  int nt = K >> 6;                     // 32 (assumes nt >= 3)
  // prologue: tile0 all 4 half-tiles, then tile1's B-halves (their steady-state slot is
  // phases 2-3 of tile -1). vmcnt(4): tile0's 8 loads landed, tile1-B may fly.
  STAGE_A8(0, 0, 0); STAGE_A8(0, 0, 1); STAGE_B8(0, 0, 0); STAGE_B8(0, 0, 1);
  STAGE_B8(1, 1, 0); STAGE_B8(1, 1, 1);
  asm volatile("s_waitcnt vmcnt(4)" ::: "memory");
  CFENCE(); __builtin_amdgcn_s_barrier(); CFENCE();

  for (int s = 0; s < nt; ++s) {
    int b = s & 1;
    bf16x8_t bfr[4][2];
    #pragma unroll
    for (int jph = 0; jph < 4; ++jph) {
      if (jph == 0) {
        #pragma unroll
        for (int ni = 0; ni < 4; ni++)
          #pragma unroll
          for (int kh = 0; kh < 2; kh++)
            bfr[ni][kh] = *(const bf16x8_t*)&Bs[b][(wn*64 + ni*16 + l16)*64 + (((kh*4 + quad) ^ (l16 & 7))*8)];
      }
      bf16x8_t af[2][2];
      #pragma unroll
      for (int i = 0; i < 2; i++)
        #pragma unroll
        for (int kh = 0; kh < 2; kh++)
          af[i][kh] = *(const bf16x8_t*)&As[b][(wm*128 + (jph*2 + i)*16 + l16)*64 + (((kh*4 + quad) ^ (l16 & 7))*8)];
      if (jph == 0) { if (s + 1 < nt) STAGE_A8(1 - b, s + 1, 0); }
      if (jph == 1) { if (s + 1 < nt) STAGE_A8(1 - b, s + 1, 1); }
      if (jph == 2) { if (s + 2 < nt) STAGE_B8(b, s + 2, 0); }
      if (jph == 3) {
        if (s + 2 < nt) {
          STAGE_B8(b, s + 2, 1);
          asm volatile("s_waitcnt vmcnt(4)" ::: "memory");
        } else {
          asm volatile("s_waitcnt vmcnt(0)" ::: "memory");
        }
      }
      CFENCE(); __builtin_amdgcn_s_barrier(); CFENCE();
      __builtin_amdgcn_s_setprio(1);
      #pragma unroll
      for (int kh = 0; kh < 2; kh++)
        #pragma unroll
        for (int i = 0; i < 2; i++)
          #pragma unroll
          for (int ni = 0; ni < 4; ni++)
            acc[jph*2 + i][ni] = mfma16(af[i][kh], bfr[ni][kh], acc[jph*2 + i][ni]);
      __builtin_amdgcn_s_setprio(0);
      CFENCE(); __builtin_amdgcn_s_barrier(); CFENCE();
    }
  }
  // C/D layout: col = lane&15, row = quad*4 + reg
  #pragma unroll
  for (int mi = 0; mi < 8; mi++)
    #pragma unroll
    for (int ni = 0; ni < 4; ni++) {
      int row0 = bm + wm*128 + mi*16 + quad*4;
      int col  = bn + wn*64 + ni*16 + l16;
      #pragma unroll
      for (int r = 0; r < 4; r++)
        Cb[(size_t)(row0 + r) * N + col] = (bf16_t)acc[mi][ni][r];
    }
#undef STAGE_A8
#undef STAGE_B8
}

// ---------------- bf16 NT GEMM v2 (round-4 2-phase): C = A B^T; out fp32 (Cf) or bf16 (Cb) ----------------
template<int BM>
__global__ __launch_bounds__(512, 1) void gemm_nt2(const bf16_t* __restrict__ A,
                                                   const bf16_t* __restrict__ Bm,
                                                   float* __restrict__ Cf, bf16_t* __restrict__ Cb,
                                                   int M, int N, int K) {
  constexpr int MR = BM / 32;     // m-frags per wave
  constexpr int RA = BM / 64;     // A staging rounds (8KB each)
  __shared__ __align__(16) bf16_t As[2][BM * 64];
  __shared__ __align__(16) bf16_t Bs[2][256 * 64];
  int tid = threadIdx.x;
  int wave = tid >> 6, lane = tid & 63;
  int quad = lane >> 4, l16 = lane & 15;
  int wm = wave >> 2, wn = wave & 3;
  int gx = gridDim.x;
  int nwg = gx * gridDim.y;
  int flat = blockIdx.y * gx + blockIdx.x;
  int swz = (flat & 7) * (nwg >> 3) + (flat >> 3);
  int bm = (swz / gx) * BM, bn = (swz % gx) * 256;
  int scol = (((tid & 7) ^ ((tid >> 3) & 7))) * 8;
  const bf16_t* pa = A + (size_t)(bm + (tid >> 3)) * K + scol;
  const bf16_t* pb = Bm + (size_t)(bn + (tid >> 3)) * K + scol;

  f32x4_t acc[MR][4];
  #pragma unroll
  for (int i = 0; i < MR; i++)
    #pragma unroll
    for (int j = 0; j < 4; j++) acc[i][j] = (f32x4_t){0.f, 0.f, 0.f, 0.f};

  int nt = K >> 6;
  #pragma unroll
  for (int r = 0; r < RA; r++) GLDS16(pa + (size_t)(r * 64) * K, &As[0][(r * 64 + wave * 8) * 64]);
  #pragma unroll
  for (int r = 0; r < 4; r++)  GLDS16(pb + (size_t)(r * 64) * K, &Bs[0][(r * 64 + wave * 8) * 64]);
  __syncthreads();

  for (int t = 0; t < nt; t++) {
    int cur = t & 1;
    if (t + 1 < nt) {
      int k1 = (t + 1) * 64;
      #pragma unroll
      for (int r = 0; r < RA; r++) GLDS16(pa + (size_t)(r * 64) * K + k1, &As[1 - cur][(r * 64 + wave * 8) * 64]);
      #pragma unroll
      for (int r = 0; r < 4; r++)  GLDS16(pb + (size_t)(r * 64) * K + k1, &Bs[1 - cur][(r * 64 + wave * 8) * 64]);
    }
    bf16x8_t bfr[4][2];
    #pragma unroll
    for (int ni = 0; ni < 4; ni++)
      #pragma unroll
      for (int kh = 0; kh < 2; kh++) {
        int blk = (kh * 4 + quad) ^ (l16 & 7);
        bfr[ni][kh] = *(const bf16x8_t*)&Bs[cur][(wn * 64 + ni * 16 + l16) * 64 + blk * 8];
      }
    #pragma unroll
    for (int g = 0; g < MR / 2; g++) {
      bf16x8_t af[2][2];
      #pragma unroll
      for (int i = 0; i < 2; i++)
        #pragma unroll
        for (int kh = 0; kh < 2; kh++) {
          int blk = (kh * 4 + quad) ^ (l16 & 7);
          af[i][kh] = *(const bf16x8_t*)&As[cur][(wm * (BM / 2) + (g * 2 + i) * 16 + l16) * 64 + blk * 8];
        }
      #pragma unroll
      for (int kh = 0; kh < 2; kh++)
        #pragma unroll
        for (int i = 0; i < 2; i++)
          #pragma unroll
          for (int ni = 0; ni < 4; ni++)
            acc[g * 2 + i][ni] = mfma16(af[i][kh], bfr[ni][kh], acc[g * 2 + i][ni]);
    }
    __syncthreads();
  }
  #pragma unroll
  for (int mi = 0; mi < MR; mi++)
    #pragma unroll
    for (int ni = 0; ni < 4; ni++) {
      int row0 = bm + wm * (BM / 2) + mi * 16 + quad * 4;
      int col  = bn + wn * 64 + ni * 16 + l16;
      if (Cb) {
        #pragma unroll
        for (int r = 0; r < 4; r++)
          Cb[(size_t)(row0 + r) * N + col] = (bf16_t)acc[mi][ni][r];
      } else {
        #pragma unroll
        for (int r = 0; r < 4; r++)
          Cf[(size_t)(row0 + r) * N + col] = acc[mi][ni][r];
      }
    }
}

// ---------------- RoPE + RMSNorm, bf16 qkv -> q/k bf16 ----------------
__global__ __launch_bounds__(256) void rope_norm_kernel(const bf16_t* __restrict__ qkv,
    const float* __restrict__ cosb, const float* __restrict__ sinb,
    bf16_t* __restrict__ qb, bf16_t* __restrict__ kb) {
  int token = blockIdx.y;
  int slot = blockIdx.x * 4 + (threadIdx.x >> 6);
  int lane = threadIdx.x & 63;
  int b = token >> 11, s = token & 2047;
  const bf16_t* row = qkv + (size_t)token * QKVD;
  int base_in = (slot < 16) ? slot * HD : C_ + (slot - 16) * HD;
  float x1 = (float)row[base_in + lane];
  float x2 = (float)row[base_in + 64 + lane];
  float c = cosb[s*64 + lane], sn = sinb[s*64 + lane];
  float y1 = x1*c + x2*sn;
  float y2 = x2*c - x1*sn;
  float ss = y1*y1 + y2*y2;
  ss += __shfl_xor(ss, 1);  ss += __shfl_xor(ss, 2);  ss += __shfl_xor(ss, 4);
  ss += __shfl_xor(ss, 8);  ss += __shfl_xor(ss, 16); ss += __shfl_xor(ss, 32);
  float r = rsqrtf(ss * (1.0f/128.0f) + 1.1920929e-07f);
  bf16_t* dst;
  if (slot < 16) {
    r *= 0.08838834764831845f * 1.4426950408889634f;  // 1/sqrt(128) * log2(e)
    dst = qb + ((size_t)(b*NH + slot) * T_ + s) * HD;
  } else {
    dst = kb + ((size_t)(b*NKV + (slot-16)) * T_ + s) * HD;
  }
  dst[lane]      = (bf16_t)(y1 * r);
  dst[lane + 64] = (bf16_t)(y2 * r);
}

// ---------------- V: transpose bf16 qkv slice to (b, kvh, d, t) ----------------
__global__ __launch_bounds__(256) void transpose_v(const bf16_t* __restrict__ qkv,
                                                   bf16_t* __restrict__ vt) {
  __shared__ bf16_t TT[64*136];   // (tok, d) pad 128->136
  int bk = blockIdx.y;            // b*8 + kv
  int b = bk >> 3, kv = bk & 7;
  int s0 = blockIdx.x * 64;
  int tid = threadIdx.x;
  int row = tid >> 2, c0 = (tid & 3) * 32;
  const bf16_t* src = qkv + (size_t)(b*T_ + s0 + row) * QKVD + C_ + KVD + kv*HD + c0;
  #pragma unroll
  for (int s4 = 0; s4 < 4; s4++)
    *(bf16x8_t*)&TT[row*136 + c0 + s4*8] = *(const bf16x8_t*)(src + s4*8);
  __syncthreads();
  #pragma unroll
  for (int s2 = 0; s2 < 2; s2++) {
    int d = (tid >> 2) + s2*64;
    #pragma unroll
    for (int s = 0; s < 2; s++) {
      int g = (tid & 3) * 8 + s*32;
      bf16x8_t pk;
      #pragma unroll
      for (int e = 0; e < 8; e++) pk[e] = TT[(g + e)*136 + d];
      *(bf16x8_t*)(vt + ((size_t)bk * HD + d) * T_ + s0 + g) = pk;
    }
  }
}

// ---------------- flash attention: split-K within block (round-3, verified) ----------------
__global__ __launch_bounds__(512, 1) void attn_kernel(const bf16_t* __restrict__ qb,
    const bf16_t* __restrict__ kb, const bf16_t* __restrict__ vt, bf16_t* __restrict__ yb) {
  __shared__ __align__(16) bf16_t Ks[2][2][64*136];   // [group][buf] (key, d) pad 128->136
  __shared__ __align__(16) bf16_t Vs[2][2][128*72];   // [group][buf] (d, key) pad 64->72
  int L = blockIdx.x;
  int bh = L & 31;
  int qt = 15 - (L >> 5);              // heavy first
  int b = bh >> 4, h = bh & 15, kvh = h >> 1;
  int tid = threadIdx.x;
  int wv = tid >> 6;                   // 0..7
  int g  = wv >> 2;                    // key group
  int sq = wv & 3;                     // q-slice
  int lane = tid & 63;
  int l32 = lane & 31, half = lane >> 5;
  int t256 = tid & 255;                // within-group thread id (256 per group)
  const bf16_t* Qp = qb + (size_t)bh * T_ * HD;
  const bf16_t* Kp = kb + (size_t)(b*NKV + kvh) * T_ * HD;
  const bf16_t* Vt = vt + (size_t)(b*NKV + kvh) * HD * T_;

  int krow = t256 >> 2, kcb = (t256 & 3) * 32;   // K staging: 64 rows x 128
  int vd = t256 >> 1,  vcb = (t256 & 1) * 32;    // V staging: 128 rows x 64

  int h0 = qt + 1;                     // tiles per group
  int kt0 = g * h0;                    // first tile of this group

  int qrow = qt*128 + sq*32 + l32;
  bf16x8_t qf[8];                      // B-frag: B[k=half*8+jj][n=l32]
  #pragma unroll
  for (int kc = 0; kc < 8; kc++)
    qf[kc] = *(const bf16x8_t*)(Qp + (size_t)qrow * HD + kc*16 + half*8);

  float mrow = -1e30f, lrow = 0.f;
  f32x16_t o[4];                       // O^T: rows = d, col = q = l32
  #pragma unroll
  for (int mb = 0; mb < 4; mb++) o[mb] = zero16();

  bf16x8_t kreg[4], vreg[4];
  {
    const bf16_t* srck = Kp + (size_t)(kt0*64 + krow) * HD + kcb;
    const bf16_t* srcv = Vt + (size_t)vd * T_ + kt0*64 + vcb;
    #pragma unroll
    for (int s2 = 0; s2 < 4; s2++) { kreg[s2] = *(const bf16x8_t*)(srck + s2*8);
                                     vreg[s2] = *(const bf16x8_t*)(srcv + s2*8); }
  }
  #pragma unroll
  for (int s2 = 0; s2 < 4; s2++) { *(bf16x8_t*)&Ks[g][0][krow*136 + kcb + s2*8] = kreg[s2];
                                   *(bf16x8_t*)&Vs[g][0][vd*72   + vcb + s2*8] = vreg[s2]; }

  for (int t = 0; t < h0; t++) {
    __syncthreads();
    int cur = t & 1;
    if (t + 1 < h0) {
      int k1 = (kt0 + t + 1) * 64;
      const bf16_t* srck = Kp + (size_t)(k1 + krow) * HD + kcb;
      const bf16_t* srcv = Vt + (size_t)vd * T_ + k1 + vcb;
      #pragma unroll
      for (int s2 = 0; s2 < 4; s2++) { kreg[s2] = *(const bf16x8_t*)(srck + s2*8);
                                       vreg[s2] = *(const bf16x8_t*)(srcv + s2*8); }
    }
    int k0 = (kt0 + t) * 64;
    f32x16_t sacc[2];
    sacc[0] = zero16(); sacc[1] = zero16();
    #pragma unroll
    for (int kc = 0; kc < 8; kc++)
      #pragma unroll
      for (int mb = 0; mb < 2; mb++) {
        bf16x8_t kf = *(const bf16x8_t*)&Ks[g][cur][(mb*32 + l32)*136 + kc*16 + half*8];
        sacc[mb] = mfma32(kf, qf[kc], sacc[mb]);
      }
    if (k0 + 63 > qt*128 + sq*32) {
      #pragma unroll
      for (int mb = 0; mb < 2; mb++)
        #pragma unroll
        for (int r = 0; r < 16; r++) {
          int key = k0 + mb*32 + (r&3) + 8*(r>>2) + 4*half;
          if (key > qrow) sacc[mb][r] = -1e30f;
        }
    }
    float mx = -1e30f;
    #pragma unroll
    for (int mb = 0; mb < 2; mb++)
      #pragma unroll
      for (int r = 0; r < 16; r++) mx = fmaxf(mx, sacc[mb][r]);
    mx = fmaxf(mx, __shfl_xor(mx, 32));
    float mnew = fmaxf(mrow, mx);
    float alpha = exp2f(mrow - mnew);
    mrow = mnew;
    float rs = 0.f;
    #pragma unroll
    for (int mb = 0; mb < 2; mb++)
      #pragma unroll
      for (int r = 0; r < 16; r++) {
        float p = exp2f(sacc[mb][r] - mnew);
        sacc[mb][r] = p;
        rs += p;
      }
    rs += __shfl_xor(rs, 32);
    lrow = lrow * alpha + rs;
    #pragma unroll
    for (int mb = 0; mb < 4; mb++) o[mb] = o[mb] * alpha;
    int P2[2][4][2];
    #pragma unroll
    for (int mb = 0; mb < 2; mb++)
      #pragma unroll
      for (int gg = 0; gg < 4; gg++) {
        P2[mb][gg][0] = pk2(sacc[mb][4*gg+0], sacc[mb][4*gg+1]);
        P2[mb][gg][1] = pk2(sacc[mb][4*gg+2], sacc[mb][4*gg+3]);
      }
    #pragma unroll
    for (int kc = 0; kc < 4; kc++) {
      int mb = kc >> 1, c = kc & 1;
      int o0 = half ? P2[mb][2*c+1][0] : P2[mb][2*c][0];
      int o1 = half ? P2[mb][2*c+1][1] : P2[mb][2*c][1];
      int s0 = half ? P2[mb][2*c][0]   : P2[mb][2*c+1][0];
      int s1 = half ? P2[mb][2*c][1]   : P2[mb][2*c+1][1];
      int r0 = __shfl_xor(s0, 32);
      int r1 = __shfl_xor(s1, 32);
      i32x4_t wvv;
      wvv[0] = half ? r0 : o0;
      wvv[1] = half ? r1 : o1;
      wvv[2] = half ? o0 : r0;
      wvv[3] = half ? o1 : r1;
      bf16x8_t pf = __builtin_bit_cast(bf16x8_t, wvv);
      #pragma unroll
      for (int mbd = 0; mbd < 4; mbd++) {
        bf16x8_t vf = *(const bf16x8_t*)&Vs[g][cur][(mbd*32 + l32)*72 + kc*16 + half*8];
        o[mbd] = mfma32(vf, pf, o[mbd]);
      }
    }
    if (t + 1 < h0) {
      #pragma unroll
      for (int s2 = 0; s2 < 4; s2++) { *(bf16x8_t*)&Ks[g][1-cur][krow*136 + kcb + s2*8] = kreg[s2];
                                       *(bf16x8_t*)&Vs[g][1-cur][vd*72   + vcb + s2*8] = vreg[s2]; }
    }
  }
  __syncthreads();
  float* MG = (float*)Vs;
  int mbase = (sq*64 + lane) * 66;
  if (g == 1) {
    #pragma unroll
    for (int mb = 0; mb < 4; mb++)
      #pragma unroll
      for (int r = 0; r < 16; r++) MG[mbase + mb*16 + r] = o[mb][r];
    MG[mbase + 64] = mrow;
    MG[mbase + 65] = lrow;
  }
  __syncthreads();
  if (g == 0) {
    float m1 = MG[mbase + 64], l1v = MG[mbase + 65];
    float mm = fmaxf(mrow, m1);
    float a0 = exp2f(mrow - mm), a1 = exp2f(m1 - mm);
    float invl = 1.0f / (lrow * a0 + l1v * a1);
    a0 *= invl; a1 *= invl;
    bf16_t* OL = &((bf16_t*)Ks)[sq * 4352];
    #pragma unroll
    for (int mb = 0; mb < 4; mb++)
      #pragma unroll
      for (int rr = 0; rr < 4; rr++) {
        bf16x4_t pk;
        #pragma unroll
        for (int jj = 0; jj < 4; jj++)
          pk[jj] = (bf16_t)(o[mb][rr*4+jj] * a0 + MG[mbase + mb*16 + rr*4 + jj] * a1);
        *(bf16x4_t*)&OL[l32*136 + mb*32 + rr*8 + half*4] = pk;
      }
    int tok = qt*128 + sq*32 + l32;
    bf16_t* dst = yb + ((size_t)(b*T_ + tok) * NH + h) * HD + half*64;
    #pragma unroll
    for (int jj = 0; jj < 8; jj++)
      *(bf16x8_t*)(dst + jj*8) = *(const bf16x8_t*)&OL[l32*136 + half*64 + jj*8];
  }
}

extern "C" void kernel_launch(void* const* d_in, const int* in_sizes, int n_in,
                              void* d_out, int out_size, void* d_ws, size_t ws_size,
                              hipStream_t stream) {
  const float* x      = (const float*)d_in[0];
  const float* w_attn = (const float*)d_in[1];
  const float* w_proj = (const float*)d_in[2];
  const float* cosb   = (const float*)d_in[3];
  const float* sinb   = (const float*)d_in[4];
  float* out = (float*)d_out;

  bf16_t* xb   = (bf16_t*)d_ws;           // 8388608
  bf16_t* wab  = xb + 8388608;            // 8388608
  bf16_t* wpb  = wab + 8388608;           // 4194304
  bf16_t* qkvb = wpb + 4194304;           // 16777216
  bf16_t* qb   = qkvb + 16777216;         // 8388608
  bf16_t* kb   = qb + 8388608;            // 4194304
  bf16_t* vt   = kb + 4194304;            // 4194304 (b, kvh, d, t)
  bf16_t* yb   = vt + 4194304;            // 8388608

  cvt3_kernel<<<20480, 256, 0, stream>>>(x, xb, w_attn, wab, w_proj, wpb);

  // qkv = x @ w_attn^T : M=4096, N=4096, K=2048 (bf16 out). 8-phase 256x256, grid 16x16
  gemm8p<<<dim3(16, 16), 512, 0, stream>>>(xb, wab, qkvb, NTOK, QKVD, C_);

  rope_norm_kernel<<<dim3(6, 4096), 256, 0, stream>>>(qkvb, cosb, sinb, qb, kb);
  transpose_v<<<dim3(32, 16), 256, 0, stream>>>(qkvb, vt);

  // 512 blocks x 512 threads: split-K within block, heavy-first dispatch, 1 block/CU (140KB LDS)
  attn_kernel<<<512, 512, 0, stream>>>(qb, kb, vt, yb);

  // out = y @ w_proj^T : M=4096, N=2048, K=2048 (fp32 out). 128x256 tiles, grid 8x32=256 blocks
  gemm_nt2<128><<<dim3(8, 32), 512, 0, stream>>>(yb, wpb, out, nullptr, NTOK, C_, C_);
}

// Round 6
// 312.133 us; speedup vs baseline: 1.0326x; 1.0326x over previous
//
#include <hip/hip_runtime.h>

#define B_ 2
#define T_ 2048
#define NH 16
#define NKV 8
#define HD 128
#define C_ 2048
#define KVD (NKV*HD)       // 1024
#define QKVD (C_ + 2*KVD)  // 4096
#define NTOK (B_*T_)       // 4096

typedef __bf16 bf16_t;
typedef __bf16 bf16x2_t __attribute__((ext_vector_type(2)));
typedef __bf16 bf16x4_t __attribute__((ext_vector_type(4)));
typedef __bf16 bf16x8_t __attribute__((ext_vector_type(8)));
typedef float f32x4_t __attribute__((ext_vector_type(4)));
typedef float f32x16_t __attribute__((ext_vector_type(16)));
typedef int i32x4_t __attribute__((ext_vector_type(4)));

__device__ __forceinline__ f32x4_t mfma16(bf16x8_t a, bf16x8_t b, f32x4_t c) {
  return __builtin_amdgcn_mfma_f32_16x16x32_bf16(a, b, c, 0, 0, 0);
}
__device__ __forceinline__ f32x16_t mfma32(bf16x8_t a, bf16x8_t b, f32x16_t c) {
  return __builtin_amdgcn_mfma_f32_32x32x16_bf16(a, b, c, 0, 0, 0);
}
__device__ __forceinline__ f32x16_t zero16() {
  f32x16_t z;
  #pragma unroll
  for (int i = 0; i < 16; i++) z[i] = 0.f;
  return z;
}
__device__ __forceinline__ int pk2(float a, float b) {
  bf16x2_t t; t[0] = (bf16_t)a; t[1] = (bf16_t)b;
  return __builtin_bit_cast(int, t);
}

// async global->LDS, 16B per lane
#define GLDS16(gp, lp) __builtin_amdgcn_global_load_lds( \
    (const __attribute__((address_space(1))) void*)(gp), \
    (__attribute__((address_space(3))) void*)(lp), 16, 0, 0)

#define CFENCE() asm volatile("" ::: "memory")

// LDS row strides for attn tiles: stride(dwords) mod 32 == 2 -> column-slice reads are
// 2-way bank-aliased only (free, m136). 136/72 were ==4 mod 32 -> 4-8-way (1.24M conflicts).
#define KSTR 132
#define VSTR 68

// ---------------- fused fp32 -> bf16 convert for x / w_attn / w_proj ----------------
__global__ __launch_bounds__(256) void cvt3_kernel(const float* __restrict__ s0, bf16_t* __restrict__ d0,
                                                   const float* __restrict__ s1, bf16_t* __restrict__ d1,
                                                   const float* __restrict__ s2, bf16_t* __restrict__ d2) {
  int bid = blockIdx.x;
  const float* s; bf16_t* d; int off;
  if (bid < 8192)       { s = s0; d = d0; off = bid; }
  else if (bid < 16384) { s = s1; d = d1; off = bid - 8192; }
  else                  { s = s2; d = d2; off = bid - 16384; }
  int i = (off * 256 + threadIdx.x) * 4;
  const float4 v = *(const float4*)(s + i);
  bf16x4_t o;
  o[0] = (bf16_t)v.x; o[1] = (bf16_t)v.y; o[2] = (bf16_t)v.z; o[3] = (bf16_t)v.w;
  *(bf16x4_t*)(d + i) = o;
}

// ---------------- 8-phase 256x256 bf16 NT GEMM (round-5, verified): C = A B^T, bf16 out ----------------
__global__ __launch_bounds__(512, 1) void gemm8p(const bf16_t* __restrict__ A,
                                                 const bf16_t* __restrict__ Bm,
                                                 bf16_t* __restrict__ Cb,
                                                 int M, int N, int K) {
  __shared__ __align__(16) bf16_t As[2][256 * 64];
  __shared__ __align__(16) bf16_t Bs[2][256 * 64];
  int tid = threadIdx.x;
  int wave = tid >> 6, lane = tid & 63;
  int quad = lane >> 4, l16 = lane & 15;
  int wm = wave >> 2, wn = wave & 3;
  int gx = gridDim.x, nwg = gx * gridDim.y;
  int flat = blockIdx.y * gx + blockIdx.x;
  int swz = (flat & 7) * (nwg >> 3) + (flat >> 3);
  int bm = (swz / gx) * 256, bn = (swz % gx) * 256;
  int scol = ((tid & 7) ^ ((tid >> 3) & 7)) * 8;
  int srow = tid >> 3;                 // 0..63
  const bf16_t* pa = A + (size_t)(bm + srow) * K + scol;
  const bf16_t* pb = Bm + (size_t)(bn + srow) * K + scol;

#define STAGE_A8(buf, tile, h) { \
    GLDS16(pa + (size_t)((h)*128 + 0) * K + (size_t)(tile)*64, &As[buf][((h)*128 + 0 + wave*8)*64]); \
    GLDS16(pa + (size_t)((h)*128 + 64) * K + (size_t)(tile)*64, &As[buf][((h)*128 + 64 + wave*8)*64]); }
#define STAGE_B8(buf, tile, h) { \
    GLDS16(pb + (size_t)((h)*128 + 0) * K + (size_t)(tile)*64, &Bs[buf][((h)*128 + 0 + wave*8)*64]); \
    GLDS16(pb + (size_t)((h)*128 + 64) * K + (size_t)(tile)*64, &Bs[buf][((h)*128 + 64 + wave*8)*64]); }

  f32x4_t acc[8][4];
  #pragma unroll
  for (int i = 0; i < 8; i++)
    #pragma unroll
    for (int j = 0; j < 4; j++) acc[i][j] = (f32x4_t){0.f, 0.f, 0.f, 0.f};

  int nt = K >> 6;                     // 32 (assumes nt >= 3)
  STAGE_A8(0, 0, 0); STAGE_A8(0, 0, 1); STAGE_B8(0, 0, 0); STAGE_B8(0, 0, 1);
  STAGE_B8(1, 1, 0); STAGE_B8(1, 1, 1);
  asm volatile("s_waitcnt vmcnt(4)" ::: "memory");
  CFENCE(); __builtin_amdgcn_s_barrier(); CFENCE();

  for (int s = 0; s < nt; ++s) {
    int b = s & 1;
    bf16x8_t bfr[4][2];
    #pragma unroll
    for (int jph = 0; jph < 4; ++jph) {
      if (jph == 0) {
        #pragma unroll
        for (int ni = 0; ni < 4; ni++)
          #pragma unroll
          for (int kh = 0; kh < 2; kh++)
            bfr[ni][kh] = *(const bf16x8_t*)&Bs[b][(wn*64 + ni*16 + l16)*64 + (((kh*4 + quad) ^ (l16 & 7))*8)];
      }
      bf16x8_t af[2][2];
      #pragma unroll
      for (int i = 0; i < 2; i++)
        #pragma unroll
        for (int kh = 0; kh < 2; kh++)
          af[i][kh] = *(const bf16x8_t*)&As[b][(wm*128 + (jph*2 + i)*16 + l16)*64 + (((kh*4 + quad) ^ (l16 & 7))*8)];
      if (jph == 0) { if (s + 1 < nt) STAGE_A8(1 - b, s + 1, 0); }
      if (jph == 1) { if (s + 1 < nt) STAGE_A8(1 - b, s + 1, 1); }
      if (jph == 2) { if (s + 2 < nt) STAGE_B8(b, s + 2, 0); }
      if (jph == 3) {
        if (s + 2 < nt) {
          STAGE_B8(b, s + 2, 1);
          asm volatile("s_waitcnt vmcnt(4)" ::: "memory");
        } else {
          asm volatile("s_waitcnt vmcnt(0)" ::: "memory");
        }
      }
      CFENCE(); __builtin_amdgcn_s_barrier(); CFENCE();
      __builtin_amdgcn_s_setprio(1);
      #pragma unroll
      for (int kh = 0; kh < 2; kh++)
        #pragma unroll
        for (int i = 0; i < 2; i++)
          #pragma unroll
          for (int ni = 0; ni < 4; ni++)
            acc[jph*2 + i][ni] = mfma16(af[i][kh], bfr[ni][kh], acc[jph*2 + i][ni]);
      __builtin_amdgcn_s_setprio(0);
      CFENCE(); __builtin_amdgcn_s_barrier(); CFENCE();
    }
  }
  #pragma unroll
  for (int mi = 0; mi < 8; mi++)
    #pragma unroll
    for (int ni = 0; ni < 4; ni++) {
      int row0 = bm + wm*128 + mi*16 + quad*4;
      int col  = bn + wn*64 + ni*16 + l16;
      #pragma unroll
      for (int r = 0; r < 4; r++)
        Cb[(size_t)(row0 + r) * N + col] = (bf16_t)acc[mi][ni][r];
    }
#undef STAGE_A8
#undef STAGE_B8
}

// ---------------- bf16 NT GEMM v2 (2-phase): C = A B^T; out fp32 (Cf) or bf16 (Cb) ----------------
template<int BM>
__global__ __launch_bounds__(512, 1) void gemm_nt2(const bf16_t* __restrict__ A,
                                                   const bf16_t* __restrict__ Bm,
                                                   float* __restrict__ Cf, bf16_t* __restrict__ Cb,
                                                   int M, int N, int K) {
  constexpr int MR = BM / 32;     // m-frags per wave
  constexpr int RA = BM / 64;     // A staging rounds (8KB each)
  __shared__ __align__(16) bf16_t As[2][BM * 64];
  __shared__ __align__(16) bf16_t Bs[2][256 * 64];
  int tid = threadIdx.x;
  int wave = tid >> 6, lane = tid & 63;
  int quad = lane >> 4, l16 = lane & 15;
  int wm = wave >> 2, wn = wave & 3;
  int gx = gridDim.x;
  int nwg = gx * gridDim.y;
  int flat = blockIdx.y * gx + blockIdx.x;
  int swz = (flat & 7) * (nwg >> 3) + (flat >> 3);
  int bm = (swz / gx) * BM, bn = (swz % gx) * 256;
  int scol = (((tid & 7) ^ ((tid >> 3) & 7))) * 8;
  const bf16_t* pa = A + (size_t)(bm + (tid >> 3)) * K + scol;
  const bf16_t* pb = Bm + (size_t)(bn + (tid >> 3)) * K + scol;

  f32x4_t acc[MR][4];
  #pragma unroll
  for (int i = 0; i < MR; i++)
    #pragma unroll
    for (int j = 0; j < 4; j++) acc[i][j] = (f32x4_t){0.f, 0.f, 0.f, 0.f};

  int nt = K >> 6;
  #pragma unroll
  for (int r = 0; r < RA; r++) GLDS16(pa + (size_t)(r * 64) * K, &As[0][(r * 64 + wave * 8) * 64]);
  #pragma unroll
  for (int r = 0; r < 4; r++)  GLDS16(pb + (size_t)(r * 64) * K, &Bs[0][(r * 64 + wave * 8) * 64]);
  __syncthreads();

  for (int t = 0; t < nt; t++) {
    int cur = t & 1;
    if (t + 1 < nt) {
      int k1 = (t + 1) * 64;
      #pragma unroll
      for (int r = 0; r < RA; r++) GLDS16(pa + (size_t)(r * 64) * K + k1, &As[1 - cur][(r * 64 + wave * 8) * 64]);
      #pragma unroll
      for (int r = 0; r < 4; r++)  GLDS16(pb + (size_t)(r * 64) * K + k1, &Bs[1 - cur][(r * 64 + wave * 8) * 64]);
    }
    bf16x8_t bfr[4][2];
    #pragma unroll
    for (int ni = 0; ni < 4; ni++)
      #pragma unroll
      for (int kh = 0; kh < 2; kh++) {
        int blk = (kh * 4 + quad) ^ (l16 & 7);
        bfr[ni][kh] = *(const bf16x8_t*)&Bs[cur][(wn * 64 + ni * 16 + l16) * 64 + blk * 8];
      }
    #pragma unroll
    for (int g = 0; g < MR / 2; g++) {
      bf16x8_t af[2][2];
      #pragma unroll
      for (int i = 0; i < 2; i++)
        #pragma unroll
        for (int kh = 0; kh < 2; kh++) {
          int blk = (kh * 4 + quad) ^ (l16 & 7);
          af[i][kh] = *(const bf16x8_t*)&As[cur][(wm * (BM / 2) + (g * 2 + i) * 16 + l16) * 64 + blk * 8];
        }
      #pragma unroll
      for (int kh = 0; kh < 2; kh++)
        #pragma unroll
        for (int i = 0; i < 2; i++)
          #pragma unroll
          for (int ni = 0; ni < 4; ni++)
            acc[g * 2 + i][ni] = mfma16(af[i][kh], bfr[ni][kh], acc[g * 2 + i][ni]);
    }
    __syncthreads();
  }
  #pragma unroll
  for (int mi = 0; mi < MR; mi++)
    #pragma unroll
    for (int ni = 0; ni < 4; ni++) {
      int row0 = bm + wm * (BM / 2) + mi * 16 + quad * 4;
      int col  = bn + wn * 64 + ni * 16 + l16;
      if (Cb) {
        #pragma unroll
        for (int r = 0; r < 4; r++)
          Cb[(size_t)(row0 + r) * N + col] = (bf16_t)acc[mi][ni][r];
      } else {
        #pragma unroll
        for (int r = 0; r < 4; r++)
          Cf[(size_t)(row0 + r) * N + col] = acc[mi][ni][r];
      }
    }
}

// ---------------- RoPE+RMSNorm AND V-transpose, fused into one launch ----------------
// blocks [0, 24576): rope (sg = bid>>12 in 0..5, token = bid & 4095) — body unchanged.
// blocks [24576, 25088): V transpose (id = bid-24576: bk = id&15, s-block = id>>4).
__global__ __launch_bounds__(256) void rope_tv_kernel(const bf16_t* __restrict__ qkv,
    const float* __restrict__ cosb, const float* __restrict__ sinb,
    bf16_t* __restrict__ qb, bf16_t* __restrict__ kb, bf16_t* __restrict__ vt) {
  __shared__ bf16_t TT[64*136];   // transpose scratch (tok, d) pad 128->136
  int bid = blockIdx.x;
  int tid = threadIdx.x;
  if (bid < 24576) {
    int token = bid & 4095;
    int slot = (bid >> 12) * 4 + (tid >> 6);
    int lane = tid & 63;
    int b = token >> 11, s = token & 2047;
    const bf16_t* row = qkv + (size_t)token * QKVD;
    int base_in = (slot < 16) ? slot * HD : C_ + (slot - 16) * HD;
    float x1 = (float)row[base_in + lane];
    float x2 = (float)row[base_in + 64 + lane];
    float c = cosb[s*64 + lane], sn = sinb[s*64 + lane];
    float y1 = x1*c + x2*sn;
    float y2 = x2*c - x1*sn;
    float ss = y1*y1 + y2*y2;
    ss += __shfl_xor(ss, 1);  ss += __shfl_xor(ss, 2);  ss += __shfl_xor(ss, 4);
    ss += __shfl_xor(ss, 8);  ss += __shfl_xor(ss, 16); ss += __shfl_xor(ss, 32);
    float r = rsqrtf(ss * (1.0f/128.0f) + 1.1920929e-07f);
    bf16_t* dst;
    if (slot < 16) {
      r *= 0.08838834764831845f * 1.4426950408889634f;  // 1/sqrt(128) * log2(e)
      dst = qb + ((size_t)(b*NH + slot) * T_ + s) * HD;
    } else {
      dst = kb + ((size_t)(b*NKV + (slot-16)) * T_ + s) * HD;
    }
    dst[lane]      = (bf16_t)(y1 * r);
    dst[lane + 64] = (bf16_t)(y2 * r);
  } else {
    int id = bid - 24576;
    int bk = id & 15;               // b*8 + kv
    int s0 = (id >> 4) * 64;
    int b = bk >> 3, kv = bk & 7;
    int row = tid >> 2, c0 = (tid & 3) * 32;
    const bf16_t* src = qkv + (size_t)(b*T_ + s0 + row) * QKVD + C_ + KVD + kv*HD + c0;
    #pragma unroll
    for (int s4 = 0; s4 < 4; s4++)
      *(bf16x8_t*)&TT[row*136 + c0 + s4*8] = *(const bf16x8_t*)(src + s4*8);
    __syncthreads();
    #pragma unroll
    for (int s2 = 0; s2 < 2; s2++) {
      int d = (tid >> 2) + s2*64;
      #pragma unroll
      for (int s = 0; s < 2; s++) {
        int g = (tid & 3) * 8 + s*32;
        bf16x8_t pk;
        #pragma unroll
        for (int e = 0; e < 8; e++) pk[e] = TT[(g + e)*136 + d];
        *(bf16x8_t*)(vt + ((size_t)bk * HD + d) * T_ + s0 + g) = pk;
      }
    }
  }
}

// ---------------- flash attention: split-K within block (round-3 structure) ----------------
// Round-6 deltas: (1) K/V LDS strides 136->132 / 72->68 (2 mod 32 dwords: 2-way bank alias
// only, was 4-8-way = 1.24M conflicts/dispatch); (2) tree max/sum reductions (serial 32-chain
// -> 5-level tree, ~-220cy dependent latency per iter); (3) T13 defer-max THR=8 (exp2 domain):
// skip o/l rescale when wave tile-max growth <= 8; P bounded by 2^8, fp32 accum fine; the
// qt=0 all-masked-lane kill still holds (mrow stays -1e30 -> merge alpha1 = 0).
__global__ __launch_bounds__(512, 1) void attn_kernel(const bf16_t* __restrict__ qb,
    const bf16_t* __restrict__ kb, const bf16_t* __restrict__ vt, bf16_t* __restrict__ yb) {
  __shared__ __align__(16) bf16_t Ks[2][2][64*KSTR];   // [group][buf] (key, d) 67584 B
  __shared__ __align__(16) bf16_t Vs[2][2][128*VSTR];  // [group][buf] (d, key) 69632 B
  int L = blockIdx.x;
  int bh = L & 31;
  int qt = 15 - (L >> 5);              // heavy first
  int b = bh >> 4, h = bh & 15, kvh = h >> 1;
  int tid = threadIdx.x;
  int wv = tid >> 6;                   // 0..7
  int g  = wv >> 2;                    // key group
  int sq = wv & 3;                     // q-slice
  int lane = tid & 63;
  int l32 = lane & 31, half = lane >> 5;
  int t256 = tid & 255;                // within-group thread id (256 per group)
  const bf16_t* Qp = qb + (size_t)bh * T_ * HD;
  const bf16_t* Kp = kb + (size_t)(b*NKV + kvh) * T_ * HD;
  const bf16_t* Vt = vt + (size_t)(b*NKV + kvh) * HD * T_;

  int krow = t256 >> 2, kcb = (t256 & 3) * 32;   // K staging: 64 rows x 128
  int vd = t256 >> 1,  vcb = (t256 & 1) * 32;    // V staging: 128 rows x 64

  int h0 = qt + 1;                     // tiles per group
  int kt0 = g * h0;                    // first tile of this group

  int qrow = qt*128 + sq*32 + l32;
  bf16x8_t qf[8];                      // B-frag: B[k=half*8+jj][n=l32]
  #pragma unroll
  for (int kc = 0; kc < 8; kc++)
    qf[kc] = *(const bf16x8_t*)(Qp + (size_t)qrow * HD + kc*16 + half*8);

  float mrow = -1e30f, lrow = 0.f;
  f32x16_t o[4];                       // O^T: rows = d, col = q = l32
  #pragma unroll
  for (int mb = 0; mb < 4; mb++) o[mb] = zero16();

  bf16x8_t kreg[4], vreg[4];
  {
    const bf16_t* srck = Kp + (size_t)(kt0*64 + krow) * HD + kcb;
    const bf16_t* srcv = Vt + (size_t)vd * T_ + kt0*64 + vcb;
    #pragma unroll
    for (int s2 = 0; s2 < 4; s2++) { kreg[s2] = *(const bf16x8_t*)(srck + s2*8);
                                     vreg[s2] = *(const bf16x8_t*)(srcv + s2*8); }
  }
  #pragma unroll
  for (int s2 = 0; s2 < 4; s2++) { *(bf16x8_t*)&Ks[g][0][krow*KSTR + kcb + s2*8] = kreg[s2];
                                   *(bf16x8_t*)&Vs[g][0][vd*VSTR  + vcb + s2*8] = vreg[s2]; }

  for (int t = 0; t < h0; t++) {
    __syncthreads();  // buf[t&1] fully staged; prior-tile reads done (uniform count both groups)
    int cur = t & 1;
    if (t + 1 < h0) {
      int k1 = (kt0 + t + 1) * 64;
      const bf16_t* srck = Kp + (size_t)(k1 + krow) * HD + kcb;
      const bf16_t* srcv = Vt + (size_t)vd * T_ + k1 + vcb;
      #pragma unroll
      for (int s2 = 0; s2 < 4; s2++) { kreg[s2] = *(const bf16x8_t*)(srck + s2*8);
                                       vreg[s2] = *(const bf16x8_t*)(srcv + s2*8); }
    }
    int k0 = (kt0 + t) * 64;
    // S^T = K Q^T
    f32x16_t sacc[2];
    sacc[0] = zero16(); sacc[1] = zero16();
    #pragma unroll
    for (int kc = 0; kc < 8; kc++)
      #pragma unroll
      for (int mb = 0; mb < 2; mb++) {
        bf16x8_t kf = *(const bf16x8_t*)&Ks[g][cur][(mb*32 + l32)*KSTR + kc*16 + half*8];
        sacc[mb] = mfma32(kf, qf[kc], sacc[mb]);
      }
    // causal mask near diagonal (false for group 0 whenever qt>=1)
    if (k0 + 63 > qt*128 + sq*32) {
      #pragma unroll
      for (int mb = 0; mb < 2; mb++)
        #pragma unroll
        for (int r = 0; r < 16; r++) {
          int key = k0 + mb*32 + (r&3) + 8*(r>>2) + 4*half;
          if (key > qrow) sacc[mb][r] = -1e30f;
        }
    }
    // tile max: 5-level tree (was serial 32-chain)
    float tm[16];
    #pragma unroll
    for (int r = 0; r < 16; r++) tm[r] = fmaxf(sacc[0][r], sacc[1][r]);
    #pragma unroll
    for (int st = 8; st >= 1; st >>= 1)
      #pragma unroll
      for (int r = 0; r < st; r++) tm[r] = fmaxf(tm[r], tm[r + st]);
    float mx = fmaxf(tm[0], __shfl_xor(tm[0], 32));
    // T13 defer-max: only rescale when the wave's max grew by > 8 (exp2 units)
    if (!__all(mx - mrow <= 8.0f)) {
      float mnew = fmaxf(mrow, mx);
      float alpha = exp2f(mrow - mnew);
      mrow = mnew;
      lrow *= alpha;
      #pragma unroll
      for (int mb = 0; mb < 4; mb++) o[mb] = o[mb] * alpha;
    }
    // P = exp2(s - mrow); row-sum via tree
    #pragma unroll
    for (int mb = 0; mb < 2; mb++)
      #pragma unroll
      for (int r = 0; r < 16; r++) sacc[mb][r] = exp2f(sacc[mb][r] - mrow);
    float ts[16];
    #pragma unroll
    for (int r = 0; r < 16; r++) ts[r] = sacc[0][r] + sacc[1][r];
    #pragma unroll
    for (int st = 8; st >= 1; st >>= 1)
      #pragma unroll
      for (int r = 0; r < st; r++) ts[r] += ts[r + st];
    lrow += ts[0] + __shfl_xor(ts[0], 32);
    // P pack: all compile-time indices
    int P2[2][4][2];
    #pragma unroll
    for (int mb = 0; mb < 2; mb++)
      #pragma unroll
      for (int gg = 0; gg < 4; gg++) {
        P2[mb][gg][0] = pk2(sacc[mb][4*gg+0], sacc[mb][4*gg+1]);
        P2[mb][gg][1] = pk2(sacc[mb][4*gg+2], sacc[mb][4*gg+3]);
      }
    // O^T += V^T P ; pf[kc] = keys kc*16 + half*8 + 0..7
    #pragma unroll
    for (int kc = 0; kc < 4; kc++) {
      int mb = kc >> 1, c = kc & 1;
      int o0 = half ? P2[mb][2*c+1][0] : P2[mb][2*c][0];
      int o1 = half ? P2[mb][2*c+1][1] : P2[mb][2*c][1];
      int s0 = half ? P2[mb][2*c][0]   : P2[mb][2*c+1][0];
      int s1 = half ? P2[mb][2*c][1]   : P2[mb][2*c+1][1];
      int r0 = __shfl_xor(s0, 32);
      int r1 = __shfl_xor(s1, 32);
      i32x4_t wvv;
      wvv[0] = half ? r0 : o0;
      wvv[1] = half ? r1 : o1;
      wvv[2] = half ? o0 : r0;
      wvv[3] = half ? o1 : r1;
      bf16x8_t pf = __builtin_bit_cast(bf16x8_t, wvv);
      #pragma unroll
      for (int mbd = 0; mbd < 4; mbd++) {
        bf16x8_t vf = *(const bf16x8_t*)&Vs[g][cur][(mbd*32 + l32)*VSTR + kc*16 + half*8];
        o[mbd] = mfma32(vf, pf, o[mbd]);
      }
    }
    if (t + 1 < h0) {
      #pragma unroll
      for (int s2 = 0; s2 < 4; s2++) { *(bf16x8_t*)&Ks[g][1-cur][krow*KSTR + kcb + s2*8] = kreg[s2];
                                       *(bf16x8_t*)&Vs[g][1-cur][vd*VSTR  + vcb + s2*8] = vreg[s2]; }
    }
  }
  // -------- merge the two key-halves (lane-aligned), then epilogue by group 0 --------
  __syncthreads();
  float* MG = (float*)Vs;              // overlay: 256 slots x 66 f32 = 67584 B (<= 69632)
  int mbase = (sq*64 + lane) * 66;     // stride 66 dwords: 2-way bank alias only (free)
  if (g == 1) {
    #pragma unroll
    for (int mb = 0; mb < 4; mb++)
      #pragma unroll
      for (int r = 0; r < 16; r++) MG[mbase + mb*16 + r] = o[mb][r];
    MG[mbase + 64] = mrow;
    MG[mbase + 65] = lrow;
  }
  __syncthreads();
  if (g == 0) {
    float m1 = MG[mbase + 64], l1v = MG[mbase + 65];
    float mm = fmaxf(mrow, m1);
    float a0 = exp2f(mrow - mm), a1 = exp2f(m1 - mm);
    float invl = 1.0f / (lrow * a0 + l1v * a1);
    a0 *= invl; a1 *= invl;
    // O^T -> LDS transpose (wave-private 32xKSTR region) -> coalesced stores
    bf16_t* OL = &((bf16_t*)Ks)[sq * (32 * KSTR)];
    #pragma unroll
    for (int mb = 0; mb < 4; mb++)
      #pragma unroll
      for (int rr = 0; rr < 4; rr++) {
        bf16x4_t pk;
        #pragma unroll
        for (int jj = 0; jj < 4; jj++)
          pk[jj] = (bf16_t)(o[mb][rr*4+jj] * a0 + MG[mbase + mb*16 + rr*4 + jj] * a1);
        *(bf16x4_t*)&OL[l32*KSTR + mb*32 + rr*8 + half*4] = pk;
      }
    int tok = qt*128 + sq*32 + l32;
    bf16_t* dst = yb + ((size_t)(b*T_ + tok) * NH + h) * HD + half*64;
    #pragma unroll
    for (int jj = 0; jj < 8; jj++)
      *(bf16x8_t*)(dst + jj*8) = *(const bf16x8_t*)&OL[l32*KSTR + half*64 + jj*8];
  }
}

extern "C" void kernel_launch(void* const* d_in, const int* in_sizes, int n_in,
                              void* d_out, int out_size, void* d_ws, size_t ws_size,
                              hipStream_t stream) {
  const float* x      = (const float*)d_in[0];
  const float* w_attn = (const float*)d_in[1];
  const float* w_proj = (const float*)d_in[2];
  const float* cosb   = (const float*)d_in[3];
  const float* sinb   = (const float*)d_in[4];
  float* out = (float*)d_out;

  bf16_t* xb   = (bf16_t*)d_ws;           // 8388608
  bf16_t* wab  = xb + 8388608;            // 8388608
  bf16_t* wpb  = wab + 8388608;           // 4194304
  bf16_t* qkvb = wpb + 4194304;           // 16777216
  bf16_t* qb   = qkvb + 16777216;         // 8388608
  bf16_t* kb   = qb + 8388608;            // 4194304
  bf16_t* vt   = kb + 4194304;            // 4194304 (b, kvh, d, t)
  bf16_t* yb   = vt + 4194304;            // 8388608

  cvt3_kernel<<<20480, 256, 0, stream>>>(x, xb, w_attn, wab, w_proj, wpb);

  // qkv = x @ w_attn^T : M=4096, N=4096, K=2048 (bf16 out). 8-phase 256x256, grid 16x16
  gemm8p<<<dim3(16, 16), 512, 0, stream>>>(xb, wab, qkvb, NTOK, QKVD, C_);

  // fused RoPE+RMSNorm (24576 blocks) + V transpose (512 blocks)
  rope_tv_kernel<<<25088, 256, 0, stream>>>(qkvb, cosb, sinb, qb, kb, vt);

  // 512 blocks x 512 threads: split-K within block, heavy-first dispatch, 1 block/CU (137KB LDS)
  attn_kernel<<<512, 512, 0, stream>>>(qb, kb, vt, yb);

  // out = y @ w_proj^T : M=4096, N=2048, K=2048 (fp32 out). 128x256 tiles, grid 8x32=256 blocks
  gemm_nt2<128><<<dim3(8, 32), 512, 0, stream>>>(yb, wpb, out, nullptr, NTOK, C_, C_);
}